// Round 12
// baseline (471.464 us; speedup 1.0000x reference)
//
#include <hip/hip_runtime.h>
#include <hip/hip_bf16.h>
#include <hip/hip_fp16.h>

#define UNITS 512
#define D_DEC 1024
#define D_ENC 1024
#define BATCH 32
#define S_LEN 2048

typedef _Float16 f16x8 __attribute__((ext_vector_type(8)));
typedef float f32x4 __attribute__((ext_vector_type(4)));

__device__ inline float tanh_fast(float x) {
    float e = __expf(2.f * x);
    return 1.f - 2.f * __builtin_amdgcn_rcpf(e + 1.f);
}

// ---------------- prep: transpose + convert W2 [1024][512] f32 -> W2h [512][1024] f16
__global__ __launch_bounds__(256) void k_prep_w2(const float* __restrict__ W2,
                                                 _Float16* __restrict__ W2h) {
    __shared__ float tile[32][33];
    const int kb = blockIdx.x * 32;
    const int nb = blockIdx.y * 32;
    const int tx = threadIdx.x;
    const int ty = threadIdx.y;
    for (int i = 0; i < 32; i += 8)
        tile[ty + i][tx] = W2[(size_t)(kb + ty + i) * UNITS + nb + tx];
    __syncthreads();
    for (int i = 0; i < 32; i += 8)
        W2h[(size_t)(nb + ty + i) * D_DEC + kb + tx] = (_Float16)tile[tx][ty + i];
}

// ---------------- query
__global__ __launch_bounds__(1024) void k_query(const float* __restrict__ dec,
                                                const float* __restrict__ W1,
                                                const float* __restrict__ b1,
                                                float* __restrict__ query) {
    const int u = blockIdx.x * 32 + (threadIdx.x & 31);
    const int b = threadIdx.x >> 5;
    float acc = b1[u];
    const float* dp = dec + (size_t)b * D_DEC;
    for (int d = 0; d < D_DEC; ++d) acc += dp[d] * W1[(size_t)d * UNITS + u];
    query[(size_t)b * UNITS + u] = acc;
}

// ---------------- fused: 128 rows x full N=512, 1024 thr / 16 waves (2m x 8n,
// wave 64x64).  Counted-vmcnt pipeline: A reg-prefetch distance 4 (pr0..pr3,
// static rotation), forced issue order [B,B,A] per step, soft barriers
// (lgkmcnt(0)+s_barrier), uniform s_waitcnt vmcnt(4) before ds_reads.
// FIFO guarantee: B(t) has 1 step of flight, A(t+1) has 2+ steps.
#define BM 128
#define BKK 32
#define NSTEP (D_DEC / BKK)

__global__ __launch_bounds__(1024, 4) void k_fused(const float* __restrict__ enc,
                                                   const _Float16* __restrict__ W2h,
                                                   const float* __restrict__ query,
                                                   const float* __restrict__ b2,
                                                   const float* __restrict__ V,
                                                   float* __restrict__ scores,
                                                   float* __restrict__ chunk_m,
                                                   float* __restrict__ chunk_l,
                                                   float* __restrict__ part_ctx) {
    __shared__ __align__(16) _Float16 Ab[2][BM * BKK];      // 2 x 8 KB
    __shared__ __align__(16) _Float16 Bb[2][UNITS * BKK];   // 2 x 32 KB
    __shared__ float sc_part[8][BM];                        // 4 KB
    __shared__ float sc_e[BM];                              // 512 B
    __shared__ float wred[4];

    const int tid  = threadIdx.x;
    const int lane = tid & 63;
    const int w    = tid >> 6;     // 0..15
    const int wr   = w >> 3;       // 0..1: rows [wr*64, +64)
    const int wc   = w & 7;        // 0..7: cols [wc*64, +64)
    const int g    = lane >> 4;    // 0..3
    const int r    = lane & 15;    // 0..15
    const int blk  = blockIdx.x;   // 0..511
    const int row0 = blk * BM;
    const int bat  = row0 >> 11;

    // A staging: thread -> row tid>>3 (0..127), float4 at (tid&7)*4
    const int arow = tid >> 3;
    const int ac4  = tid & 7;
    const float* aptr = enc + (size_t)(row0 + arow) * D_ENC + ac4 * 4;
    const int a_wbyte = arow * 64 + ((ac4 * 8) ^ (((arow >> 1) & 3) << 4));

    f32x4 acc[4][4];
#pragma unroll
    for (int i = 0; i < 4; ++i)
#pragma unroll
        for (int j = 0; j < 4; ++j) acc[i][j] = (f32x4){0.f, 0.f, 0.f, 0.f};

    auto gldB = [&](int t) {
        const int k0 = t * BKK;
        _Float16* dstb = &Bb[t & 1][0];
#pragma unroll
        for (int i = 0; i < 2; ++i) {
            const int g16 = i * 1024 + tid;          // 0..2047 16B granules
            const int n   = g16 >> 2;                // 0..511
            const int j   = g16 & 3;
            const int kel = ((j * 16) ^ (((n >> 1) & 3) << 4)) >> 1;
            const _Float16* src = W2h + (size_t)n * D_DEC + k0 + kel;
            __builtin_amdgcn_global_load_lds(
                (const __attribute__((address_space(1))) void*)src,
                (__attribute__((address_space(3))) void*)(dstb + g16 * 8), 16, 0, 0);
        }
    };
    auto cvtA = [&](const float4& p, int buf) {
        _Float16 h[4] = {(_Float16)p.x, (_Float16)p.y, (_Float16)p.z, (_Float16)p.w};
        *reinterpret_cast<float2*>((char*)&Ab[buf][0] + a_wbyte) =
            *reinterpret_cast<float2*>(h);
    };

#define COMPUTE(T) do {                                                              \
    f16x8 af[4], bf[4];                                                              \
    _Pragma("unroll") for (int q = 0; q < 4; ++q) {                                  \
        const int rowa = wr * 64 + q * 16 + r;                                       \
        const int off  = rowa * 64 + ((g * 16) ^ (((rowa >> 1) & 3) << 4));          \
        af[q] = *reinterpret_cast<const f16x8*>((const char*)&Ab[(T) & 1][0] + off); \
    }                                                                                \
    _Pragma("unroll") for (int q = 0; q < 4; ++q) {                                  \
        const int rowb = wc * 64 + q * 16 + r;                                       \
        const int off  = rowb * 64 + ((g * 16) ^ (((rowb >> 1) & 3) << 4));          \
        bf[q] = *reinterpret_cast<const f16x8*>((const char*)&Bb[(T) & 1][0] + off); \
    }                                                                                \
    _Pragma("unroll") for (int fr = 0; fr < 4; ++fr)                                 \
        _Pragma("unroll") for (int fc = 0; fc < 4; ++fc)                             \
            acc[fr][fc] = __builtin_amdgcn_mfma_f32_16x16x32_f16(                    \
                af[fr], bf[fc], acc[fr][fc], 0, 0, 0);                               \
} while (0)

#define STEPU(U, PW, PC) do {                                                        \
    const int t = q4 + (U);                                                          \
    if (t < 31) {                                                                    \
        gldB(t + 1);                                                                 \
        __builtin_amdgcn_sched_barrier(0);                                           \
        const int ta = (t + 4 > 31) ? 31 : (t + 4);                                  \
        PW = *reinterpret_cast<const float4*>(aptr + ta * BKK);                      \
        asm volatile("s_waitcnt vmcnt(4)" ::: "memory");                             \
        COMPUTE(t);                                                                  \
        cvtA(PC, (t + 1) & 1);                                                       \
        asm volatile("s_waitcnt lgkmcnt(0)" ::: "memory");                           \
        __builtin_amdgcn_s_barrier();                                                \
    } else {                                                                         \
        asm volatile("s_waitcnt vmcnt(0)" ::: "memory");                             \
        COMPUTE(t);                                                                  \
    }                                                                                \
} while (0)

    // ---- prologue: B(0) staged; A(1..3) in reg-flight; A(0) written to LDS.
    float4 pr0, pr1, pr2, pr3;
    gldB(0);
    __builtin_amdgcn_sched_barrier(0);
    pr1 = *reinterpret_cast<const float4*>(aptr + 1 * BKK);
    pr2 = *reinterpret_cast<const float4*>(aptr + 2 * BKK);
    pr3 = *reinterpret_cast<const float4*>(aptr + 3 * BKK);
    pr0 = *reinterpret_cast<const float4*>(aptr);        // A(0)
    cvtA(pr0, 0);                                        // waits all -> B(0) landed
    __syncthreads();

    // ---- main loop: 8 quads x 4 unrolled steps, static pr rotation
    for (int q4 = 0; q4 < NSTEP; q4 += 4) {
        STEPU(0, pr0, pr1);
        STEPU(1, pr1, pr2);
        STEPU(2, pr2, pr3);
        STEPU(3, pr3, pr0);
    }
#undef STEPU
#undef COMPUTE

    // ---- epilogue 1: per-wave tanh*V partials over its 64-col group
    float qv[4], vv[4];
#pragma unroll
    for (int fc = 0; fc < 4; ++fc) {
        const int col = wc * 64 + fc * 16 + r;
        qv[fc] = query[(size_t)bat * UNITS + col] + b2[col];
        vv[fc] = V[col];
    }
    float ps[4][4];
#pragma unroll
    for (int fr = 0; fr < 4; ++fr)
#pragma unroll
        for (int i = 0; i < 4; ++i) ps[fr][i] = 0.f;
#pragma unroll
    for (int fc = 0; fc < 4; ++fc)
#pragma unroll
        for (int fr = 0; fr < 4; ++fr)
#pragma unroll
            for (int i = 0; i < 4; ++i)
                ps[fr][i] += tanh_fast(acc[fr][fc][i] + qv[fc]) * vv[fc];
#pragma unroll
    for (int off = 1; off < 16; off <<= 1)
#pragma unroll
        for (int fr = 0; fr < 4; ++fr)
#pragma unroll
            for (int i = 0; i < 4; ++i)
                ps[fr][i] += __shfl_xor(ps[fr][i], off, 64);
    __syncthreads();
    if (r == 0)
#pragma unroll
        for (int fr = 0; fr < 4; ++fr)
#pragma unroll
            for (int i = 0; i < 4; ++i)
                sc_part[wc][wr * 64 + fr * 16 + g * 4 + i] = ps[fr][i];
    __syncthreads();

    // ---- epilogue 2: chunk softmax stats over 128 rows (2 waves)
    float s_val = 0.f;
    if (tid < BM) {
#pragma unroll
        for (int ww = 0; ww < 8; ++ww) s_val += sc_part[ww][tid];
        scores[(size_t)row0 + tid] = s_val;
        float m = s_val;
#pragma unroll
        for (int off = 32; off; off >>= 1) m = fmaxf(m, __shfl_xor(m, off, 64));
        if ((tid & 63) == 0) wred[tid >> 6] = m;
    }
    __syncthreads();
    if (tid < BM) {
        const float M = fmaxf(wred[0], wred[1]);
        const float e = __expf(s_val - M);
        sc_e[tid] = e;
        float l = e;
#pragma unroll
        for (int off = 32; off; off >>= 1) l += __shfl_xor(l, off, 64);
        if ((tid & 63) == 0) wred[2 + (tid >> 6)] = l;
    }
    __syncthreads();
    if (tid == 0) {
        chunk_m[blk] = fmaxf(wred[0], wred[1]);
        chunk_l[blk] = wred[2] + wred[3];
    }

    // ---- epilogue 3: partial context from this block's (cache-hot) enc tile
    {
        const int d = tid;                 // 0..1023 = one column each
        float cx = 0.f;
        const float* ebase = enc + (size_t)row0 * D_ENC + d;
#pragma unroll 4
        for (int i = 0; i < BM; ++i)
            cx += sc_e[i] * ebase[(size_t)i * D_ENC];
        part_ctx[(size_t)blk * D_ENC + d] = cx;
    }
}

// ---------------- combine: per batch, merge 16 chunks (flash rescale)
__global__ __launch_bounds__(256) void k_combine(const float* __restrict__ scores,
                                                 const float* __restrict__ chunk_m,
                                                 const float* __restrict__ chunk_l,
                                                 const float* __restrict__ part_ctx,
                                                 float* __restrict__ out_ctx,
                                                 float* __restrict__ out_w) {
    const int b = blockIdx.x;
    const int tid = threadIdx.x;
    __shared__ float fc[16];
    __shared__ float Msh, Lsh;
    if (tid < 16) {
        const float m = chunk_m[b * 16 + tid];
        float M = m;
#pragma unroll
        for (int off = 8; off; off >>= 1) M = fmaxf(M, __shfl_xor(M, off, 16));
        const float f = __expf(m - M);
        float lf = chunk_l[b * 16 + tid] * f;
#pragma unroll
        for (int off = 8; off; off >>= 1) lf += __shfl_xor(lf, off, 16);
        fc[tid] = f;
        if (tid == 0) { Msh = M; Lsh = lf; }
    }
    __syncthreads();
    const float M = Msh;
    const float invL = 1.f / Lsh;
#pragma unroll
    for (int j = 0; j < 8; ++j) {
        const int s = tid + j * 256;
        out_w[(size_t)b * S_LEN + s] = __expf(scores[(size_t)b * S_LEN + s] - M) * invL;
    }
#pragma unroll
    for (int j = 0; j < 4; ++j) {
        const int d = tid + j * 256;
        float sacc = 0.f;
        for (int c = 0; c < 16; ++c)
            sacc += part_ctx[(size_t)(b * 16 + c) * D_ENC + d] * fc[c];
        out_ctx[(size_t)b * D_ENC + d] = sacc * invL;
    }
}

extern "C" void kernel_launch(void* const* d_in, const int* in_sizes, int n_in,
                              void* d_out, int out_size, void* d_ws, size_t ws_size,
                              hipStream_t stream) {
    const float* dec = (const float*)d_in[0];
    const float* enc = (const float*)d_in[1];
    const float* W1  = (const float*)d_in[2];
    const float* b1  = (const float*)d_in[3];
    const float* W2  = (const float*)d_in[4];
    const float* b2  = (const float*)d_in[5];
    const float* V   = (const float*)d_in[6];
    // bv unused: softmax shift-invariant

    float* out = (float*)d_out;
    float* out_ctx = out;                 // [32,1024]
    float* out_w   = out + BATCH * D_ENC; // [32,2048]

    char* ws = (char*)d_ws;
    _Float16* W2h  = (_Float16*)(ws);                          // 1 MB
    float* query   = (float*)(ws + (1 << 20));                 // 64 KB
    float* scores  = (float*)(ws + (1 << 20) + (1 << 16));     // 256 KB
    float* chunk_m = (float*)(ws + (1 << 20) + (1 << 16) + (1 << 18));          // 2 KB
    float* chunk_l = (float*)(ws + (1 << 20) + (1 << 16) + (1 << 18) + 4096);   // 2 KB
    float* part_ctx = (float*)(ws + (1 << 20) + (1 << 16) + (1 << 18) + 8192);  // 2 MB

    k_prep_w2<<<dim3(D_DEC / 32, UNITS / 32), dim3(32, 8), 0, stream>>>(W2, W2h);
    k_query<<<UNITS / 32, 1024, 0, stream>>>(dec, W1, b1, query);
    k_fused<<<(BATCH * S_LEN) / BM, 1024, 0, stream>>>(enc, W2h, query, b2, V,
                                                       scores, chunk_m, chunk_l, part_ctx);
    k_combine<<<BATCH, 256, 0, stream>>>(scores, chunk_m, chunk_l, part_ctx,
                                         out_ctx, out_w);
}

// Round 13
// 338.530 us; speedup vs baseline: 1.3927x; 1.3927x over previous
//
#include <hip/hip_runtime.h>
#include <hip/hip_bf16.h>
#include <hip/hip_fp16.h>

#define UNITS 512
#define D_DEC 1024
#define D_ENC 1024
#define BATCH 32
#define S_LEN 2048

typedef _Float16 f16x8 __attribute__((ext_vector_type(8)));
typedef float f32x4 __attribute__((ext_vector_type(4)));

__device__ inline float tanh_fast(float x) {
    float e = __expf(2.f * x);
    return 1.f - 2.f * __builtin_amdgcn_rcpf(e + 1.f);
}

// ---------------- prep: transpose + convert W2 [1024][512] f32 -> W2h [512][1024] f16
__global__ __launch_bounds__(256) void k_prep_w2(const float* __restrict__ W2,
                                                 _Float16* __restrict__ W2h) {
    __shared__ float tile[32][33];
    const int kb = blockIdx.x * 32;
    const int nb = blockIdx.y * 32;
    const int tx = threadIdx.x;
    const int ty = threadIdx.y;
    for (int i = 0; i < 32; i += 8)
        tile[ty + i][tx] = W2[(size_t)(kb + ty + i) * UNITS + nb + tx];
    __syncthreads();
    for (int i = 0; i < 32; i += 8)
        W2h[(size_t)(nb + ty + i) * D_DEC + kb + tx] = (_Float16)tile[tx][ty + i];
}

// ---------------- query
__global__ __launch_bounds__(1024) void k_query(const float* __restrict__ dec,
                                                const float* __restrict__ W1,
                                                const float* __restrict__ b1,
                                                float* __restrict__ query) {
    const int u = blockIdx.x * 32 + (threadIdx.x & 31);
    const int b = threadIdx.x >> 5;
    float acc = b1[u];
    const float* dp = dec + (size_t)b * D_DEC;
    for (int d = 0; d < D_DEC; ++d) acc += dp[d] * W1[(size_t)d * UNITS + u];
    query[(size_t)b * UNITS + u] = acc;
}

// ---------------- fused: 64 rows x full N=512 per block, 1024 thr / 16 waves
// (wave tile 64x32, acc=32 regs).  r8's proven single-barrier dbuf loop, but
// 2 blocks/CU x 16 waves = 32 waves/CU (max): one block's barrier drain hides
// under the other block's compute (m114 TLP).  __launch_bounds__(1024,8) caps
// VGPR at 64 so 8 waves/SIMD are actually allowed.
#define BM 64
#define BKK 32
#define NSTEP (D_DEC / BKK)

__global__ __launch_bounds__(1024, 8) void k_fused(const float* __restrict__ enc,
                                                   const _Float16* __restrict__ W2h,
                                                   const float* __restrict__ query,
                                                   const float* __restrict__ b2,
                                                   const float* __restrict__ V,
                                                   float* __restrict__ scores,
                                                   float* __restrict__ chunk_m,
                                                   float* __restrict__ chunk_l,
                                                   float* __restrict__ part_ctx) {
    __shared__ __align__(16) _Float16 Ab[2][BM * BKK];      // 2 x 4 KB
    __shared__ __align__(16) _Float16 Bb[2][UNITS * BKK];   // 2 x 32 KB
    __shared__ float sc_part[16][BM];                       // 4 KB
    __shared__ float sc_e[BM];                              // 256 B

    const int tid  = threadIdx.x;
    const int lane = tid & 63;
    const int w    = tid >> 6;     // 0..15: cols [w*32, +32)
    const int g    = lane >> 4;    // 0..3
    const int r    = lane & 15;    // 0..15
    const int blk  = blockIdx.x;   // 0..1023
    const int row0 = blk * BM;
    const int bat  = row0 >> 11;

    // A staging: thread -> row tid>>4 (0..63), float2 at k = (tid&15)*2
    const int arow = tid >> 4;
    const int ac2  = tid & 15;
    const float* aptr = enc + (size_t)(row0 + arow) * D_ENC + ac2 * 2;
    const int a_wbyte = arow * 64 + ((ac2 * 4) ^ (((arow >> 1) & 3) << 4));

    f32x4 acc[4][2];
#pragma unroll
    for (int i = 0; i < 4; ++i)
#pragma unroll
        for (int j = 0; j < 2; ++j) acc[i][j] = (f32x4){0.f, 0.f, 0.f, 0.f};

    auto gldB = [&](int t) {
        const int k0 = t * BKK;
        _Float16* dstb = &Bb[t & 1][0];
#pragma unroll
        for (int i = 0; i < 2; ++i) {
            const int g16 = i * 1024 + tid;          // 0..2047 16B granules
            const int n   = g16 >> 2;                // 0..511
            const int j   = g16 & 3;
            const int kel = ((j * 16) ^ (((n >> 1) & 3) << 4)) >> 1;
            const _Float16* src = W2h + (size_t)n * D_DEC + k0 + kel;
            __builtin_amdgcn_global_load_lds(
                (const __attribute__((address_space(1))) void*)src,
                (__attribute__((address_space(3))) void*)(dstb + g16 * 8), 16, 0, 0);
        }
    };
    auto cvtA = [&](const float2& p, int buf) {
        _Float16 h[2] = {(_Float16)p.x, (_Float16)p.y};
        *reinterpret_cast<unsigned*>((char*)&Ab[buf][0] + a_wbyte) =
            *reinterpret_cast<unsigned*>(h);
    };

    // ---- prologue: B(0) staged; A(0) written.
    gldB(0);
    cvtA(*reinterpret_cast<const float2*>(aptr), 0);
    __syncthreads();

    // ---- main loop: one barrier per step (r8 structure)
    for (int t = 0; t < NSTEP; ++t) {
        const int cur = t & 1;
        float2 pn;
        if (t + 1 < NSTEP) {
            gldB(t + 1);
            pn = *reinterpret_cast<const float2*>(aptr + (t + 1) * BKK);
        }

        const char* Ac = (const char*)&Ab[cur][0];
        const char* Bc = (const char*)&Bb[cur][0];
        f16x8 bf[2];
#pragma unroll
        for (int fc = 0; fc < 2; ++fc) {
            const int rowb = w * 32 + fc * 16 + r;
            bf[fc] = *reinterpret_cast<const f16x8*>(
                Bc + rowb * 64 + ((g * 16) ^ (((rowb >> 1) & 3) << 4)));
        }
#pragma unroll
        for (int fr = 0; fr < 4; ++fr) {
            const int rowa = fr * 16 + r;
            const f16x8 af = *reinterpret_cast<const f16x8*>(
                Ac + rowa * 64 + ((g * 16) ^ (((rowa >> 1) & 3) << 4)));
#pragma unroll
            for (int fc = 0; fc < 2; ++fc)
                acc[fr][fc] = __builtin_amdgcn_mfma_f32_16x16x32_f16(
                    af, bf[fc], acc[fr][fc], 0, 0, 0);
        }

        if (t + 1 < NSTEP) cvtA(pn, cur ^ 1);
        __syncthreads();
    }

    // ---- epilogue 1: per-wave tanh*V partials over its 32-col group
    float qv[2], vv[2];
#pragma unroll
    for (int fc = 0; fc < 2; ++fc) {
        const int col = w * 32 + fc * 16 + r;
        qv[fc] = query[(size_t)bat * UNITS + col] + b2[col];
        vv[fc] = V[col];
    }
    float ps[4][4];
#pragma unroll
    for (int fr = 0; fr < 4; ++fr)
#pragma unroll
        for (int i = 0; i < 4; ++i) ps[fr][i] = 0.f;
#pragma unroll
    for (int fc = 0; fc < 2; ++fc)
#pragma unroll
        for (int fr = 0; fr < 4; ++fr)
#pragma unroll
            for (int i = 0; i < 4; ++i)
                ps[fr][i] += tanh_fast(acc[fr][fc][i] + qv[fc]) * vv[fc];
#pragma unroll
    for (int off = 1; off < 16; off <<= 1)
#pragma unroll
        for (int fr = 0; fr < 4; ++fr)
#pragma unroll
            for (int i = 0; i < 4; ++i)
                ps[fr][i] += __shfl_xor(ps[fr][i], off, 64);
    if (r == 0)
#pragma unroll
        for (int fr = 0; fr < 4; ++fr)
#pragma unroll
            for (int i = 0; i < 4; ++i)
                sc_part[w][fr * 16 + g * 4 + i] = ps[fr][i];
    __syncthreads();

    // ---- epilogue 2: chunk softmax stats (one wave; bv dropped)
    if (tid < BM) {
        float s = 0.f;
#pragma unroll
        for (int ww = 0; ww < 16; ++ww) s += sc_part[ww][tid];
        scores[(size_t)row0 + tid] = s;
        float m = s;
#pragma unroll
        for (int off = 32; off; off >>= 1) m = fmaxf(m, __shfl_xor(m, off, 64));
        const float e = __expf(s - m);
        float l = e;
#pragma unroll
        for (int off = 32; off; off >>= 1) l += __shfl_xor(l, off, 64);
        sc_e[tid] = e;
        if (tid == 0) { chunk_m[blk] = m; chunk_l[blk] = l; }
    }
    __syncthreads();

    // ---- epilogue 3: partial context from this block's (cache-hot) enc tile
    {
        const int d = tid;                 // 0..1023, one column each
        float cx = 0.f;
        const float* ebase = enc + (size_t)row0 * D_ENC + d;
#pragma unroll 4
        for (int i = 0; i < BM; ++i)
            cx += sc_e[i] * ebase[(size_t)i * D_ENC];
        part_ctx[(size_t)blk * D_ENC + d] = cx;
    }
}

// ---------------- combine: per batch, merge 32 chunks (flash rescale)
__global__ __launch_bounds__(256) void k_combine(const float* __restrict__ scores,
                                                 const float* __restrict__ chunk_m,
                                                 const float* __restrict__ chunk_l,
                                                 const float* __restrict__ part_ctx,
                                                 float* __restrict__ out_ctx,
                                                 float* __restrict__ out_w) {
    const int b = blockIdx.x;
    const int tid = threadIdx.x;
    __shared__ float fc[32];
    __shared__ float Msh, Lsh;
    if (tid < 32) {
        const float m = chunk_m[b * 32 + tid];
        float M = m;
#pragma unroll
        for (int off = 16; off; off >>= 1) M = fmaxf(M, __shfl_xor(M, off, 64));
        const float f = __expf(m - M);
        float lf = chunk_l[b * 32 + tid] * f;
#pragma unroll
        for (int off = 16; off; off >>= 1) lf += __shfl_xor(lf, off, 64);
        fc[tid] = f;
        if (tid == 0) { Msh = M; Lsh = lf; }
    }
    __syncthreads();
    const float M = Msh;
    const float invL = 1.f / Lsh;
#pragma unroll
    for (int j = 0; j < 8; ++j) {
        const int s = tid + j * 256;
        out_w[(size_t)b * S_LEN + s] = __expf(scores[(size_t)b * S_LEN + s] - M) * invL;
    }
#pragma unroll
    for (int j = 0; j < 4; ++j) {
        const int d = tid + j * 256;
        float sacc = 0.f;
        for (int c = 0; c < 32; ++c)
            sacc += part_ctx[(size_t)(b * 32 + c) * D_ENC + d] * fc[c];
        out_ctx[(size_t)b * D_ENC + d] = sacc * invL;
    }
}

extern "C" void kernel_launch(void* const* d_in, const int* in_sizes, int n_in,
                              void* d_out, int out_size, void* d_ws, size_t ws_size,
                              hipStream_t stream) {
    const float* dec = (const float*)d_in[0];
    const float* enc = (const float*)d_in[1];
    const float* W1  = (const float*)d_in[2];
    const float* b1  = (const float*)d_in[3];
    const float* W2  = (const float*)d_in[4];
    const float* b2  = (const float*)d_in[5];
    const float* V   = (const float*)d_in[6];
    // bv unused: softmax shift-invariant

    float* out = (float*)d_out;
    float* out_ctx = out;                 // [32,1024]
    float* out_w   = out + BATCH * D_ENC; // [32,2048]

    char* ws = (char*)d_ws;
    _Float16* W2h  = (_Float16*)(ws);                          // 1 MB
    float* query   = (float*)(ws + (1 << 20));                 // 64 KB
    float* scores  = (float*)(ws + (1 << 20) + (1 << 16));     // 256 KB
    float* chunk_m = (float*)(ws + (1 << 20) + (1 << 16) + (1 << 18));          // 4 KB
    float* chunk_l = (float*)(ws + (1 << 20) + (1 << 16) + (1 << 18) + 4096);   // 4 KB
    float* part_ctx = (float*)(ws + (1 << 20) + (1 << 16) + (1 << 18) + 8192);  // 4 MB

    k_prep_w2<<<dim3(D_DEC / 32, UNITS / 32), dim3(32, 8), 0, stream>>>(W2, W2h);
    k_query<<<UNITS / 32, 1024, 0, stream>>>(dec, W1, b1, query);
    k_fused<<<(BATCH * S_LEN) / BM, 1024, 0, stream>>>(enc, W2h, query, b2, V,
                                                       scores, chunk_m, chunk_l, part_ctx);
    k_combine<<<BATCH, 256, 0, stream>>>(scores, chunk_m, chunk_l, part_ctx,
                                         out_ctx, out_w);
}

// Round 14
// 208.069 us; speedup vs baseline: 2.2659x; 1.6270x over previous
//
#include <hip/hip_runtime.h>
#include <hip/hip_bf16.h>
#include <hip/hip_fp16.h>

#define UNITS 512
#define D_DEC 1024
#define D_ENC 1024
#define BATCH 32
#define S_LEN 2048

typedef _Float16 f16x8 __attribute__((ext_vector_type(8)));
typedef float f32x4 __attribute__((ext_vector_type(4)));

__device__ inline float tanh_fast(float x) {
    float e = __expf(2.f * x);
    return 1.f - 2.f * __builtin_amdgcn_rcpf(e + 1.f);
}

// ---------------- prep: transpose + convert W2 [1024][512] f32 -> W2h [512][1024] f16
__global__ __launch_bounds__(256) void k_prep_w2(const float* __restrict__ W2,
                                                 _Float16* __restrict__ W2h) {
    __shared__ float tile[32][33];
    const int kb = blockIdx.x * 32;
    const int nb = blockIdx.y * 32;
    const int tx = threadIdx.x;
    const int ty = threadIdx.y;
    for (int i = 0; i < 32; i += 8)
        tile[ty + i][tx] = W2[(size_t)(kb + ty + i) * UNITS + nb + tx];
    __syncthreads();
    for (int i = 0; i < 32; i += 8)
        W2h[(size_t)(nb + ty + i) * D_DEC + kb + tx] = (_Float16)tile[tx][ty + i];
}

// ---------------- query
__global__ __launch_bounds__(1024) void k_query(const float* __restrict__ dec,
                                                const float* __restrict__ W1,
                                                const float* __restrict__ b1,
                                                float* __restrict__ query) {
    const int u = blockIdx.x * 32 + (threadIdx.x & 31);
    const int b = threadIdx.x >> 5;
    float acc = b1[u];
    const float* dp = dec + (size_t)b * D_DEC;
    for (int d = 0; d < D_DEC; ++d) acc += dp[d] * W1[(size_t)d * UNITS + u];
    query[(size_t)b * UNITS + u] = acc;
}

// ---------------- fused: 128 rows x full N=512, 1024 thr / 16 waves (2m x 8n,
// wave 64x64) — r11 geometry, but counted-vmcnt soft barriers:
// per step: issue B(t+1)^2 -> issue A(t+2) -> COMPUTE -> cvt A(t+1)
// (compiler vmcnt(3)) -> s_waitcnt vmcnt(1) (publish own B before barrier) ->
// lgkmcnt(0) -> s_barrier.  Exactly one A-load stays in flight across every
// barrier; B lands under COMPUTE's cover.  Issue order enforced with
// sched_barrier(0) so the FIFO arithmetic holds (m152-safe).
#define BM 128
#define BKK 32
#define NSTEP (D_DEC / BKK)

__global__ __launch_bounds__(1024, 4) void k_fused(const float* __restrict__ enc,
                                                   const _Float16* __restrict__ W2h,
                                                   const float* __restrict__ query,
                                                   const float* __restrict__ b2,
                                                   const float* __restrict__ V,
                                                   float* __restrict__ scores,
                                                   float* __restrict__ chunk_m,
                                                   float* __restrict__ chunk_l,
                                                   float* __restrict__ part_ctx) {
    __shared__ __align__(16) _Float16 Ab[2][BM * BKK];      // 2 x 8 KB
    __shared__ __align__(16) _Float16 Bb[2][UNITS * BKK];   // 2 x 32 KB
    __shared__ float sc_part[8][BM];                        // 4 KB
    __shared__ float sc_e[BM];                              // 512 B
    __shared__ float wred[4];

    const int tid  = threadIdx.x;
    const int lane = tid & 63;
    const int w    = tid >> 6;     // 0..15
    const int wr   = w >> 3;       // 0..1: rows [wr*64, +64)
    const int wc   = w & 7;        // 0..7: cols [wc*64, +64)
    const int g    = lane >> 4;    // 0..3
    const int r    = lane & 15;    // 0..15
    const int blk  = blockIdx.x;   // 0..511
    const int row0 = blk * BM;
    const int bat  = row0 >> 11;

    // A staging: thread -> row tid>>3 (0..127), float4 at (tid&7)*4
    const int arow = tid >> 3;
    const int ac4  = tid & 7;
    const float* aptr = enc + (size_t)(row0 + arow) * D_ENC + ac4 * 4;
    const int a_wbyte = arow * 64 + ((ac4 * 8) ^ (((arow >> 1) & 3) << 4));

    f32x4 acc[4][4];
#pragma unroll
    for (int i = 0; i < 4; ++i)
#pragma unroll
        for (int j = 0; j < 4; ++j) acc[i][j] = (f32x4){0.f, 0.f, 0.f, 0.f};

    auto gldB = [&](int t) {
        const int k0 = t * BKK;
        _Float16* dstb = &Bb[t & 1][0];
#pragma unroll
        for (int i = 0; i < 2; ++i) {
            const int g16 = i * 1024 + tid;          // 0..2047 16B granules
            const int n   = g16 >> 2;                // 0..511
            const int j   = g16 & 3;
            const int kel = ((j * 16) ^ (((n >> 1) & 3) << 4)) >> 1;
            const _Float16* src = W2h + (size_t)n * D_DEC + k0 + kel;
            __builtin_amdgcn_global_load_lds(
                (const __attribute__((address_space(1))) void*)src,
                (__attribute__((address_space(3))) void*)(dstb + g16 * 8), 16, 0, 0);
        }
    };
    auto cvtA = [&](const float4& p, int buf) {
        _Float16 h[4] = {(_Float16)p.x, (_Float16)p.y, (_Float16)p.z, (_Float16)p.w};
        *reinterpret_cast<float2*>((char*)&Ab[buf][0] + a_wbyte) =
            *reinterpret_cast<float2*>(h);
    };
    auto compute = [&](const _Float16* Abuf, const _Float16* Bbuf) {
        f16x8 af[4], bf[4];
#pragma unroll
        for (int q = 0; q < 4; ++q) {
            const int rowa = wr * 64 + q * 16 + r;
            const int off  = rowa * 64 + ((g * 16) ^ (((rowa >> 1) & 3) << 4));
            af[q] = *reinterpret_cast<const f16x8*>((const char*)Abuf + off);
        }
#pragma unroll
        for (int q = 0; q < 4; ++q) {
            const int rowb = wc * 64 + q * 16 + r;
            const int off  = rowb * 64 + ((g * 16) ^ (((rowb >> 1) & 3) << 4));
            bf[q] = *reinterpret_cast<const f16x8*>((const char*)Bbuf + off);
        }
#pragma unroll
        for (int fr = 0; fr < 4; ++fr)
#pragma unroll
            for (int fc = 0; fc < 4; ++fc)
                acc[fr][fc] = __builtin_amdgcn_mfma_f32_16x16x32_f16(
                    af[fr], bf[fc], acc[fr][fc], 0, 0, 0);
    };

    // ---- prologue: A(0) cvt'd; A(1) in regs; B(0) staged; full drain once.
    float4 pnA, pnB;
    {
        const float4 p0 = *reinterpret_cast<const float4*>(aptr);
        pnA = *reinterpret_cast<const float4*>(aptr + BKK);
        gldB(0);
        cvtA(p0, 0);
        __syncthreads();   // drains everything; pnA value is landed & valid
    }

#define FULL_STEP(T, CUR, PN_CVT, PN_LOAD)                                      \
    do {                                                                        \
        gldB((T) + 1);                                                          \
        __builtin_amdgcn_sched_barrier(0);                                      \
        PN_LOAD = *reinterpret_cast<const float4*>(aptr + ((T) + 2) * BKK);     \
        __builtin_amdgcn_sched_barrier(0);                                      \
        compute(&Ab[CUR][0], &Bb[CUR][0]);                                      \
        cvtA(PN_CVT, (CUR) ^ 1);                                                \
        asm volatile("s_waitcnt vmcnt(1)" ::: "memory");                        \
        asm volatile("s_waitcnt lgkmcnt(0)" ::: "memory");                      \
        __builtin_amdgcn_s_barrier();                                           \
        __builtin_amdgcn_sched_barrier(0);                                      \
    } while (0)

    // ---- main loop: steps 0..29 as pairs (static buffer indices + pn rotation)
    for (int tp = 0; tp < 15; ++tp) {
        FULL_STEP(2 * tp,     0, pnA, pnB);
        FULL_STEP(2 * tp + 1, 1, pnB, pnA);
    }
#undef FULL_STEP
    // ---- t = 30: no A(32) load
    {
        gldB(31);
        __builtin_amdgcn_sched_barrier(0);
        compute(&Ab[0][0], &Bb[0][0]);
        cvtA(pnA, 1);                       // A(31); compiler waits vmcnt(2)
        asm volatile("s_waitcnt vmcnt(0)" ::: "memory");
        asm volatile("s_waitcnt lgkmcnt(0)" ::: "memory");
        __builtin_amdgcn_s_barrier();
        __builtin_amdgcn_sched_barrier(0);
    }
    // ---- t = 31: compute only
    compute(&Ab[1][0], &Bb[1][0]);

    // ---- epilogue 1: per-wave tanh*V partials over its 64-col group
    float qv[4], vv[4];
#pragma unroll
    for (int fc = 0; fc < 4; ++fc) {
        const int col = wc * 64 + fc * 16 + r;
        qv[fc] = query[(size_t)bat * UNITS + col] + b2[col];
        vv[fc] = V[col];
    }
    float ps[4][4];
#pragma unroll
    for (int fr = 0; fr < 4; ++fr)
#pragma unroll
        for (int i = 0; i < 4; ++i) ps[fr][i] = 0.f;
#pragma unroll
    for (int fc = 0; fc < 4; ++fc)
#pragma unroll
        for (int fr = 0; fr < 4; ++fr)
#pragma unroll
            for (int i = 0; i < 4; ++i)
                ps[fr][i] += tanh_fast(acc[fr][fc][i] + qv[fc]) * vv[fc];
#pragma unroll
    for (int off = 1; off < 16; off <<= 1)
#pragma unroll
        for (int fr = 0; fr < 4; ++fr)
#pragma unroll
            for (int i = 0; i < 4; ++i)
                ps[fr][i] += __shfl_xor(ps[fr][i], off, 64);
    __syncthreads();
    if (r == 0)
#pragma unroll
        for (int fr = 0; fr < 4; ++fr)
#pragma unroll
            for (int i = 0; i < 4; ++i)
                sc_part[wc][wr * 64 + fr * 16 + g * 4 + i] = ps[fr][i];
    __syncthreads();

    // ---- epilogue 2: chunk softmax stats over 128 rows (2 waves)
    float s_val = 0.f;
    if (tid < BM) {
#pragma unroll
        for (int ww = 0; ww < 8; ++ww) s_val += sc_part[ww][tid];
        scores[(size_t)row0 + tid] = s_val;
        float m = s_val;
#pragma unroll
        for (int off = 32; off; off >>= 1) m = fmaxf(m, __shfl_xor(m, off, 64));
        if ((tid & 63) == 0) wred[tid >> 6] = m;
    }
    __syncthreads();
    if (tid < BM) {
        const float M = fmaxf(wred[0], wred[1]);
        const float e = __expf(s_val - M);
        sc_e[tid] = e;
        float l = e;
#pragma unroll
        for (int off = 32; off; off >>= 1) l += __shfl_xor(l, off, 64);
        if ((tid & 63) == 0) wred[2 + (tid >> 6)] = l;
    }
    __syncthreads();
    if (tid == 0) {
        chunk_m[blk] = fmaxf(wred[0], wred[1]);
        chunk_l[blk] = wred[2] + wred[3];
    }

    // ---- epilogue 3: partial context from this block's (cache-hot) enc tile
    {
        const int d = tid;                 // 0..1023 = one column each
        float cx = 0.f;
        const float* ebase = enc + (size_t)row0 * D_ENC + d;
#pragma unroll 4
        for (int i = 0; i < BM; ++i)
            cx += sc_e[i] * ebase[(size_t)i * D_ENC];
        part_ctx[(size_t)blk * D_ENC + d] = cx;
    }
}

// ---------------- combine: per batch, merge 16 chunks (flash rescale)
__global__ __launch_bounds__(256) void k_combine(const float* __restrict__ scores,
                                                 const float* __restrict__ chunk_m,
                                                 const float* __restrict__ chunk_l,
                                                 const float* __restrict__ part_ctx,
                                                 float* __restrict__ out_ctx,
                                                 float* __restrict__ out_w) {
    const int b = blockIdx.x;
    const int tid = threadIdx.x;
    __shared__ float fc[16];
    __shared__ float Msh, Lsh;
    if (tid < 16) {
        const float m = chunk_m[b * 16 + tid];
        float M = m;
#pragma unroll
        for (int off = 8; off; off >>= 1) M = fmaxf(M, __shfl_xor(M, off, 16));
        const float f = __expf(m - M);
        float lf = chunk_l[b * 16 + tid] * f;
#pragma unroll
        for (int off = 8; off; off >>= 1) lf += __shfl_xor(lf, off, 16);
        fc[tid] = f;
        if (tid == 0) { Msh = M; Lsh = lf; }
    }
    __syncthreads();
    const float M = Msh;
    const float invL = 1.f / Lsh;
#pragma unroll
    for (int j = 0; j < 8; ++j) {
        const int s = tid + j * 256;
        out_w[(size_t)b * S_LEN + s] = __expf(scores[(size_t)b * S_LEN + s] - M) * invL;
    }
#pragma unroll
    for (int j = 0; j < 4; ++j) {
        const int d = tid + j * 256;
        float sacc = 0.f;
        for (int c = 0; c < 16; ++c)
            sacc += part_ctx[(size_t)(b * 16 + c) * D_ENC + d] * fc[c];
        out_ctx[(size_t)b * D_ENC + d] = sacc * invL;
    }
}

extern "C" void kernel_launch(void* const* d_in, const int* in_sizes, int n_in,
                              void* d_out, int out_size, void* d_ws, size_t ws_size,
                              hipStream_t stream) {
    const float* dec = (const float*)d_in[0];
    const float* enc = (const float*)d_in[1];
    const float* W1  = (const float*)d_in[2];
    const float* b1  = (const float*)d_in[3];
    const float* W2  = (const float*)d_in[4];
    const float* b2  = (const float*)d_in[5];
    const float* V   = (const float*)d_in[6];
    // bv unused: softmax shift-invariant

    float* out = (float*)d_out;
    float* out_ctx = out;                 // [32,1024]
    float* out_w   = out + BATCH * D_ENC; // [32,2048]

    char* ws = (char*)d_ws;
    _Float16* W2h  = (_Float16*)(ws);                          // 1 MB
    float* query   = (float*)(ws + (1 << 20));                 // 64 KB
    float* scores  = (float*)(ws + (1 << 20) + (1 << 16));     // 256 KB
    float* chunk_m = (float*)(ws + (1 << 20) + (1 << 16) + (1 << 18));          // 2 KB
    float* chunk_l = (float*)(ws + (1 << 20) + (1 << 16) + (1 << 18) + 4096);   // 2 KB
    float* part_ctx = (float*)(ws + (1 << 20) + (1 << 16) + (1 << 18) + 8192);  // 2 MB

    k_prep_w2<<<dim3(D_DEC / 32, UNITS / 32), dim3(32, 8), 0, stream>>>(W2, W2h);
    k_query<<<UNITS / 32, 1024, 0, stream>>>(dec, W1, b1, query);
    k_fused<<<(BATCH * S_LEN) / BM, 1024, 0, stream>>>(enc, W2h, query, b2, V,
                                                       scores, chunk_m, chunk_l, part_ctx);
    k_combine<<<BATCH, 256, 0, stream>>>(scores, chunk_m, chunk_l, part_ctx,
                                         out_ctx, out_w);
}